// Round 1
// baseline (2266.096 us; speedup 1.0000x reference)
//
#include <hip/hip_runtime.h>

#define NB 4
#define NC 512
#define ND 64      // C8
#define HWOUT 4096 // 64*64
#define SPIN 6400  // 80*80

// ---------------- bilinear resize 80x80 -> 64x64, 512 ch, 4 batch ----------------
__global__ __launch_bounds__(256) void resize_kernel(const float* __restrict__ X,
                                                     float* __restrict__ Y) {
  int idx = blockIdx.x * 256 + threadIdx.x;
  if (idx >= NB * NC * HWOUT) return;
  int ox = idx & 63;
  int oy = (idx >> 6) & 63;
  int bc = idx >> 12;
  float sy = fmaxf((oy + 0.5f) * 1.25f - 0.5f, 0.f);
  float sx = fmaxf((ox + 0.5f) * 1.25f - 0.5f, 0.f);
  int y0 = (int)sy; int y1 = min(y0 + 1, 79); float wy = sy - (float)y0;
  int x0 = (int)sx; int x1 = min(x0 + 1, 79); float wx = sx - (float)x0;
  const float* Xp = X + (size_t)bc * SPIN;
  float v00 = Xp[y0 * 80 + x0], v01 = Xp[y0 * 80 + x1];
  float v10 = Xp[y1 * 80 + x0], v11 = Xp[y1 * 80 + x1];
  float r0 = v00 + (v01 - v00) * wx;
  float r1 = v10 + (v11 - v10) * wx;
  Y[idx] = r0 + (r1 - r0) * wy;
}

// ---------------- conv1x1 as GEMM: Y[b][o][p] = sum_c W[o][c]*X[b][c][p] + bias[o]
// C = 512 fixed. Tile: 64 o x 64 p, K-chunk 32. 256 threads, 4x4 micro-tile.
__global__ __launch_bounds__(256) void conv1x1_kernel(const float* __restrict__ X,
                                                      const float* __restrict__ W,
                                                      const float* __restrict__ bias,
                                                      float* __restrict__ Y,
                                                      int P, int O) {
  __shared__ float Xs[32 * 66];
  __shared__ float Ws[64 * 34];
  int b = blockIdx.z, o0 = blockIdx.y * 64, p0 = blockIdx.x * 64;
  int t = threadIdx.x;
  int tx = t & 15, ty = t >> 4;
  float acc[4][4] = {};
  const float* Xb = X + (size_t)b * NC * P;
  for (int c0 = 0; c0 < NC; c0 += 32) {
#pragma unroll
    for (int k = 0; k < 8; ++k) {
      int idx = t + k * 256;
      int p = idx & 63, c = idx >> 6;
      Xs[c * 66 + p] = Xb[(size_t)(c0 + c) * P + p0 + p];
    }
#pragma unroll
    for (int k = 0; k < 8; ++k) {
      int idx = t + k * 256;
      int cc = idx & 31, o = idx >> 5;
      Ws[o * 34 + cc] = W[(size_t)(o0 + o) * NC + c0 + cc];
    }
    __syncthreads();
#pragma unroll
    for (int cc = 0; cc < 32; ++cc) {
      float xv[4], wv[4];
#pragma unroll
      for (int j = 0; j < 4; ++j) xv[j] = Xs[cc * 66 + tx * 4 + j];
#pragma unroll
      for (int i = 0; i < 4; ++i) wv[i] = Ws[(ty * 4 + i) * 34 + cc];
#pragma unroll
      for (int i = 0; i < 4; ++i)
#pragma unroll
        for (int j = 0; j < 4; ++j) acc[i][j] += wv[i] * xv[j];
    }
    __syncthreads();
  }
#pragma unroll
  for (int i = 0; i < 4; ++i) {
    float bv = bias[o0 + ty * 4 + i];
#pragma unroll
    for (int j = 0; j < 4; ++j)
      Y[((size_t)b * O + o0 + ty * 4 + i) * P + p0 + tx * 4 + j] = acc[i][j] + bv;
  }
}

// ---------------- flash attention (no max-tracking) + write mid ----------------
// F,G: (B,64,4096)  H: (B,512,4096)  MID: (B,512,4096)
// block: (m-tile of 32, batch). 256 threads.
__global__ __launch_bounds__(256) void attn_kernel(const float* __restrict__ F,
                                                   const float* __restrict__ G,
                                                   const float* __restrict__ H,
                                                   float* __restrict__ MID) {
  __shared__ float Qs[32 * 65];
  __shared__ float Ks[64 * 65];
  __shared__ float Ps[32 * 65];
  __shared__ float Vs[64 * 132];
  __shared__ float den[32];

  int b = blockIdx.y;
  int m0 = blockIdx.x * 32;
  int t = threadIdx.x;
  const float* Fb = F + (size_t)b * ND * HWOUT;
  const float* Gb = G + (size_t)b * ND * HWOUT;
  const float* Hb = H + (size_t)b * NC * HWOUT;

#pragma unroll
  for (int k = 0; k < 8; ++k) {
    int idx = t + k * 256;
    int mi = idx & 31, c = idx >> 5;
    Qs[mi * 65 + c] = Fb[(size_t)c * HWOUT + m0 + mi];
  }
  if (t < 32) den[t] = 0.f;

  float acc[4][16];
#pragma unroll
  for (int q = 0; q < 4; ++q)
#pragma unroll
    for (int r = 0; r < 16; ++r) acc[q][r] = 0.f;

  const int tx = t & 15;   // c-group for PV
  const int ty = t >> 4;   // mi-group for PV
  const int cl0 = tx * 8;
  const int mi0 = ty * 2;
  const int smi = t & 31;        // S phase row
  const int sn0 = (t >> 5) * 8;  // S phase col base

  for (int n0 = 0; n0 < HWOUT; n0 += 64) {
    __syncthreads();  // prior tile fully consumed
    // stage K tile: Ks[ni][c]
#pragma unroll
    for (int k = 0; k < 16; ++k) {
      int idx = t + k * 256;
      int ni = idx & 63, c = idx >> 6;
      Ks[ni * 65 + c] = Gb[(size_t)c * HWOUT + n0 + ni];
    }
    __syncthreads();
    // S = Q K^T ; P = exp(S)
    float sv[8];
#pragma unroll
    for (int j = 0; j < 8; ++j) sv[j] = 0.f;
    for (int c = 0; c < 64; ++c) {
      float q = Qs[smi * 65 + c];
#pragma unroll
      for (int j = 0; j < 8; ++j) sv[j] += q * Ks[(sn0 + j) * 65 + c];
    }
#pragma unroll
    for (int j = 0; j < 8; ++j) Ps[smi * 65 + sn0 + j] = __expf(sv[j]);
    __syncthreads();
    if (t < 32) {
      float rs = 0.f;
      for (int ni = 0; ni < 64; ++ni) rs += Ps[t * 65 + ni];
      den[t] += rs;
    }
    // PV in 4 channel-chunks of 128
#pragma unroll
    for (int ch = 0; ch < 4; ++ch) {
      __syncthreads();  // prev chunk compute (or den phase) done
#pragma unroll
      for (int k = 0; k < 32; ++k) {
        int idx = t + k * 256;
        int ni = idx & 63, c = idx >> 6;  // c in 0..127
        Vs[ni * 132 + c] = Hb[(size_t)(ch * 128 + c) * HWOUT + n0 + ni];
      }
      __syncthreads();
      for (int ni = 0; ni < 64; ++ni) {
        float p0 = Ps[mi0 * 65 + ni];
        float p1 = Ps[(mi0 + 1) * 65 + ni];
        float4 va = *(const float4*)&Vs[ni * 132 + cl0];
        float4 vb = *(const float4*)&Vs[ni * 132 + cl0 + 4];
        float vv[8] = {va.x, va.y, va.z, va.w, vb.x, vb.y, vb.z, vb.w};
#pragma unroll
        for (int i = 0; i < 8; ++i) {
          acc[ch][i * 2 + 0] += p0 * vv[i];
          acc[ch][i * 2 + 1] += p1 * vv[i];
        }
      }
    }
  }
  __syncthreads();
  float d0 = 1.f / den[mi0];
  float d1 = 1.f / den[mi0 + 1];
  float* Mb = MID + (size_t)b * NC * HWOUT;
#pragma unroll
  for (int ch = 0; ch < 4; ++ch)
#pragma unroll
    for (int i = 0; i < 8; ++i) {
      int c = ch * 128 + cl0 + i;
      Mb[(size_t)c * HWOUT + m0 + mi0] = acc[ch][i * 2 + 0] * d0;
      Mb[(size_t)c * HWOUT + m0 + mi0 + 1] = acc[ch][i * 2 + 1] * d1;
    }
}

extern "C" void kernel_launch(void* const* d_in, const int* in_sizes, int n_in,
                              void* d_out, int out_size, void* d_ws, size_t ws_size,
                              hipStream_t stream) {
  const float* content = (const float*)d_in[0];  // (4,512,64,64)
  const float* style   = (const float*)d_in[1];  // (4,512,80,80)
  const float* f_w = (const float*)d_in[2];
  const float* f_b = (const float*)d_in[3];
  const float* g_w = (const float*)d_in[4];
  const float* g_b = (const float*)d_in[5];
  const float* h_w = (const float*)d_in[6];
  const float* h_b = (const float*)d_in[7];
  const float* out_w = (const float*)d_in[8];
  const float* out_b = (const float*)d_in[9];
  float* out = (float*)d_out;

  float* ws = (float*)d_ws;
  // layout (floats): f[1M] g[1M] h[8M] styr_mid[8M]
  float* f_buf = ws;
  float* g_buf = ws + (size_t)NB * ND * HWOUT;
  float* h_buf = g_buf + (size_t)NB * ND * HWOUT;
  float* styr  = h_buf + (size_t)NB * NC * HWOUT;  // reused as mid after g,h
  float* mid   = styr;

  // 1. resize style -> styr
  resize_kernel<<<dim3((NB * NC * HWOUT + 255) / 256), 256, 0, stream>>>(style, styr);
  // 2. f = f_w @ content + f_b
  conv1x1_kernel<<<dim3(HWOUT / 64, ND / 64, NB), 256, 0, stream>>>(content, f_w, f_b, f_buf, HWOUT, ND);
  // 3. g = g_w @ styr + g_b
  conv1x1_kernel<<<dim3(HWOUT / 64, ND / 64, NB), 256, 0, stream>>>(styr, g_w, g_b, g_buf, HWOUT, ND);
  // 4. h = h_w @ styr + h_b
  conv1x1_kernel<<<dim3(HWOUT / 64, NC / 64, NB), 256, 0, stream>>>(styr, h_w, h_b, h_buf, HWOUT, NC);
  // 5. attention -> mid (overwrites styr, which is dead now)
  attn_kernel<<<dim3(HWOUT / 32, NB), 256, 0, stream>>>(f_buf, g_buf, h_buf, mid);
  // 6. out = out_w @ mid + out_b
  conv1x1_kernel<<<dim3(HWOUT / 64, NC / 64, NB), 256, 0, stream>>>(mid, out_w, out_b, out, HWOUT, NC);
}

// Round 2
// 432.816 us; speedup vs baseline: 5.2357x; 5.2357x over previous
//
#include <hip/hip_runtime.h>

#define NB 4
#define NC 512
#define ND 64
#define HW 4096
#define SPIN 6400

typedef _Float16 f16;
typedef _Float16 f16x8 __attribute__((ext_vector_type(8)));
typedef short s16x8 __attribute__((ext_vector_type(8)));
typedef float f32x4 __attribute__((ext_vector_type(4)));

__device__ __forceinline__ unsigned short f32_to_bf16(float x) {
  union { float f; unsigned u; } v; v.f = x;
  unsigned r = v.u + 0x7FFFu + ((v.u >> 16) & 1u);
  return (unsigned short)(r >> 16);
}

__device__ __forceinline__ void stv(float* p, float v) { *p = v; }
__device__ __forceinline__ void stv(f16* p, float v) { *p = (f16)v; }
__device__ __forceinline__ void stv(unsigned short* p, float v) { *p = f32_to_bf16(v); }

// ---------------- weight convert f32 -> f16 ----------------
__global__ __launch_bounds__(256) void cvt_kernel(const float* __restrict__ in,
                                                  f16* __restrict__ out, int n) {
  int i = blockIdx.x * 256 + threadIdx.x;
  if (i < n) out[i] = (f16)in[i];
}

// ---------------- bilinear resize 80x80 -> 64x64 (f32 ch-major) ----------------
__global__ __launch_bounds__(256) void resize_kernel(const float* __restrict__ X,
                                                     float* __restrict__ Y) {
  int idx = blockIdx.x * 256 + threadIdx.x;
  if (idx >= NB * NC * HW) return;
  int ox = idx & 63;
  int oy = (idx >> 6) & 63;
  int bc = idx >> 12;
  float sy = fmaxf((oy + 0.5f) * 1.25f - 0.5f, 0.f);
  float sx = fmaxf((ox + 0.5f) * 1.25f - 0.5f, 0.f);
  int y0 = (int)sy; int y1 = min(y0 + 1, 79); float wy = sy - (float)y0;
  int x0 = (int)sx; int x1 = min(x0 + 1, 79); float wx = sx - (float)x0;
  const float* Xp = X + (size_t)bc * SPIN;
  float v00 = Xp[y0 * 80 + x0], v01 = Xp[y0 * 80 + x1];
  float v10 = Xp[y1 * 80 + x0], v11 = Xp[y1 * 80 + x1];
  float r0 = v00 + (v01 - v00) * wx;
  float r1 = v10 + (v11 - v10) * wx;
  Y[idx] = r0 + (r1 - r0) * wy;
}

// ---------------- transpose+cvt: f32 [b][512][4096] -> f16 [b][4096][512] ----------------
__global__ __launch_bounds__(256) void tcvt_kernel(const float* __restrict__ in,
                                                   f16* __restrict__ out) {
  __shared__ float Xs[64][65];
  int p0 = blockIdx.x * 64, c0 = blockIdx.y * 64, b = blockIdx.z;
  int t = threadIdx.x;
  const float* ib = in + ((size_t)b * NC + c0) * HW + p0;
  int pl = t & 63, cg = t >> 6;
#pragma unroll
  for (int k = 0; k < 16; ++k) {
    int c = cg * 16 + k;
    Xs[c][pl] = ib[(size_t)c * HW + pl];
  }
  __syncthreads();
  int p = t >> 2, cb = (t & 3) * 16;
  union { f16 h[16]; float4 q[2]; } u;
#pragma unroll
  for (int j = 0; j < 16; ++j) u.h[j] = (f16)Xs[cb + j][p];
  f16* ob = out + ((size_t)b * HW + p0 + p) * NC + c0 + cb;
  *(float4*)(ob) = u.q[0];
  *(float4*)(ob + 8) = u.q[1];
}

// ---------------- conv1x1, position-major out (O=64): Y[b][p][o] = X[b][p][:]·W[o][:] + bias
__global__ __launch_bounds__(256) void convpm_kernel(const f16* __restrict__ X,
                                                     const f16* __restrict__ W,
                                                     const float* __restrict__ bias,
                                                     f16* __restrict__ Y) {
  int b = blockIdx.z;
  int t = threadIdx.x, l = t & 63, w = t >> 6;
  int pw = blockIdx.x * 256 + w * 64;
  int l4 = l & 15, g = l >> 4;
  f32x4 acc[4][4] = {};
  const f16* Xb = X + ((size_t)b * HW + pw) * NC;
  for (int kk = 0; kk < 16; ++kk) {
    int co = kk * 32 + g * 8;
    f16x8 a[4], bb[4];
#pragma unroll
    for (int ms = 0; ms < 4; ++ms) a[ms] = *(const f16x8*)(Xb + (size_t)(ms * 16 + l4) * NC + co);
#pragma unroll
    for (int ct = 0; ct < 4; ++ct) bb[ct] = *(const f16x8*)(W + (size_t)(ct * 16 + l4) * NC + co);
#pragma unroll
    for (int ms = 0; ms < 4; ++ms)
#pragma unroll
      for (int ct = 0; ct < 4; ++ct)
        acc[ms][ct] = __builtin_amdgcn_mfma_f32_16x16x32_f16(a[ms], bb[ct], acc[ms][ct], 0, 0, 0);
  }
  float bv[4];
#pragma unroll
  for (int ct = 0; ct < 4; ++ct) bv[ct] = bias[ct * 16 + l4];
  f16* Yb = Y + ((size_t)b * HW + pw) * ND;
#pragma unroll
  for (int ms = 0; ms < 4; ++ms)
#pragma unroll
    for (int ct = 0; ct < 4; ++ct)
#pragma unroll
      for (int r = 0; r < 4; ++r)
        Yb[(size_t)(ms * 16 + g * 4 + r) * ND + ct * 16 + l4] = (f16)(acc[ms][ct][r] + bv[ct]);
}

// ---------------- conv1x1, channel-major out: Y[b][o][p] = W[o][:]·X[b][p][:] + bias
template <typename OUT_T>
__global__ __launch_bounds__(256) void convcm_kernel(const f16* __restrict__ X,
                                                     const f16* __restrict__ W,
                                                     const float* __restrict__ bias,
                                                     OUT_T* __restrict__ Y, int O) {
  int b = blockIdx.z;
  int o0 = blockIdx.x * 64;
  int t = threadIdx.x, l = t & 63, w = t >> 6;
  int pw = blockIdx.y * 256 + w * 64;
  int l4 = l & 15, g = l >> 4;
  f32x4 acc[4][4] = {};
  const f16* Xb = X + ((size_t)b * HW + pw) * NC;
  const f16* Wb = W + (size_t)o0 * NC;
  for (int kk = 0; kk < 16; ++kk) {
    int co = kk * 32 + g * 8;
    f16x8 a[4], bb[4];
#pragma unroll
    for (int ms = 0; ms < 4; ++ms) a[ms] = *(const f16x8*)(Wb + (size_t)(ms * 16 + l4) * NC + co);
#pragma unroll
    for (int ct = 0; ct < 4; ++ct) bb[ct] = *(const f16x8*)(Xb + (size_t)(ct * 16 + l4) * NC + co);
#pragma unroll
    for (int ms = 0; ms < 4; ++ms)
#pragma unroll
      for (int ct = 0; ct < 4; ++ct)
        acc[ms][ct] = __builtin_amdgcn_mfma_f32_16x16x32_f16(a[ms], bb[ct], acc[ms][ct], 0, 0, 0);
  }
  float bv[4][4];
#pragma unroll
  for (int ms = 0; ms < 4; ++ms)
#pragma unroll
    for (int r = 0; r < 4; ++r) bv[ms][r] = bias[o0 + ms * 16 + g * 4 + r];
#pragma unroll
  for (int ms = 0; ms < 4; ++ms)
#pragma unroll
    for (int ct = 0; ct < 4; ++ct)
#pragma unroll
      for (int r = 0; r < 4; ++r) {
        float val = acc[ms][ct][r] + bv[ms][r];
        stv(&Y[((size_t)b * O + o0 + ms * 16 + g * 4 + r) * HW + pw + ct * 16 + l4], val);
      }
}

// ---------------- flash attention (MFMA, no max-tracking) ----------------
// FT,GT: f16 [b][4096][64] pos-major; HC: bf16 [b][512][4096] ch-major; MIDT: f16 [b][4096][512]
__global__ __launch_bounds__(256, 2) void attn_kernel(const f16* __restrict__ FT,
                                                      const f16* __restrict__ GT,
                                                      const unsigned short* __restrict__ HC,
                                                      f16* __restrict__ MIDT) {
  __shared__ __align__(16) char KsB[64 * 128];
  __shared__ __align__(16) char PsB[64 * 128];
  __shared__ float denS[64];
  int bid = blockIdx.x;
  // XCD-grouped swizzle: batch b pinned to XCD pair {2b,2b+1} so its 4MB V stays L2-hot
  int b = (bid & 7) >> 1;
  int mt = ((bid >> 3) << 1) | (bid & 1);
  int m0 = mt * 64;
  int t = threadIdx.x, l = t & 63, w = t >> 6;
  int l4 = l & 15, g = l >> 4;

  const f16* Fb = FT + ((size_t)b * HW + m0 + w * 16 + l4) * ND;
  f16x8 qa0 = *(const f16x8*)(Fb + g * 8);
  f16x8 qa1 = *(const f16x8*)(Fb + 32 + g * 8);

  f32x4 acc[4][8] = {};
  float den_acc[4] = {0.f, 0.f, 0.f, 0.f};

  const f16* Gb = GT + (size_t)b * HW * ND;
  const unsigned short* Hb = HC + ((size_t)b * NC + w * 128) * HW;

  for (int n0 = 0; n0 < HW; n0 += 64) {
    __syncthreads();  // prev-iter Ks/Ps consumed
#pragma unroll
    for (int i = 0; i < 2; ++i) {
      int idx = t + i * 256;
      int nl = idx >> 3, cc = idx & 7;
      f16x8 kv = *(const f16x8*)(Gb + (size_t)(n0 + nl) * ND + cc * 8);
      *(f16x8*)(KsB + ((nl * 128 + cc * 16) ^ ((nl & 7) << 4))) = kv;
    }
    __syncthreads();
    float dp[4] = {0.f, 0.f, 0.f, 0.f};
#pragma unroll
    for (int ns = 0; ns < 4; ++ns) {
      int n = ns * 16 + l4;
      int sw = (n & 7) << 4;
      f16x8 kb0 = *(const f16x8*)(KsB + ((n * 128 + g * 16) ^ sw));
      f16x8 kb1 = *(const f16x8*)(KsB + ((n * 128 + 64 + g * 16) ^ sw));
      f32x4 s = {};
      s = __builtin_amdgcn_mfma_f32_16x16x32_f16(qa0, kb0, s, 0, 0, 0);
      s = __builtin_amdgcn_mfma_f32_16x16x32_f16(qa1, kb1, s, 0, 0, 0);
#pragma unroll
      for (int r = 0; r < 4; ++r) {
        float p = __expf(s[r]);
        dp[r] += p;
        int row = w * 16 + g * 4 + r;
        *(unsigned short*)(PsB + ((row * 128 + (ns * 16 + l4) * 2) ^ ((row & 7) << 4))) =
            f32_to_bf16(p);
      }
    }
#pragma unroll
    for (int r = 0; r < 4; ++r) {
      float v = dp[r];
      v += __shfl_xor(v, 1); v += __shfl_xor(v, 2);
      v += __shfl_xor(v, 4); v += __shfl_xor(v, 8);
      den_acc[r] += v;
    }
    __syncthreads();  // P visible to all waves
    s16x8 pa[4][2];
#pragma unroll
    for (int ms = 0; ms < 4; ++ms) {
      int row = ms * 16 + l4;
      int sw = (row & 7) << 4;
      pa[ms][0] = *(const s16x8*)(PsB + ((row * 128 + g * 16) ^ sw));
      pa[ms][1] = *(const s16x8*)(PsB + ((row * 128 + 64 + g * 16) ^ sw));
    }
#pragma unroll
    for (int ct = 0; ct < 8; ++ct) {
      const unsigned short* hp = Hb + (size_t)(ct * 16 + l4) * HW + n0 + g * 8;
      s16x8 vb0 = *(const s16x8*)(hp);
      s16x8 vb1 = *(const s16x8*)(hp + 32);
#pragma unroll
      for (int ms = 0; ms < 4; ++ms) {
        acc[ms][ct] = __builtin_amdgcn_mfma_f32_16x16x32_bf16(pa[ms][0], vb0, acc[ms][ct], 0, 0, 0);
        acc[ms][ct] = __builtin_amdgcn_mfma_f32_16x16x32_bf16(pa[ms][1], vb1, acc[ms][ct], 0, 0, 0);
      }
    }
  }
  if (l4 == 0) {
#pragma unroll
    for (int r = 0; r < 4; ++r) denS[w * 16 + g * 4 + r] = den_acc[r];
  }
  __syncthreads();
  float rd[4][4];
#pragma unroll
  for (int ms = 0; ms < 4; ++ms)
#pragma unroll
    for (int r = 0; r < 4; ++r) rd[ms][r] = 1.f / denS[ms * 16 + g * 4 + r];
  f16* Mb = MIDT + ((size_t)b * HW + m0) * NC + w * 128;
#pragma unroll
  for (int ms = 0; ms < 4; ++ms)
#pragma unroll
    for (int ct = 0; ct < 8; ++ct)
#pragma unroll
      for (int r = 0; r < 4; ++r)
        Mb[(size_t)(ms * 16 + g * 4 + r) * NC + ct * 16 + l4] = (f16)(acc[ms][ct][r] * rd[ms][r]);
}

extern "C" void kernel_launch(void* const* d_in, const int* in_sizes, int n_in,
                              void* d_out, int out_size, void* d_ws, size_t ws_size,
                              hipStream_t stream) {
  const float* content = (const float*)d_in[0];
  const float* style   = (const float*)d_in[1];
  const float* f_w = (const float*)d_in[2];
  const float* f_b = (const float*)d_in[3];
  const float* g_w = (const float*)d_in[4];
  const float* g_b = (const float*)d_in[5];
  const float* h_w = (const float*)d_in[6];
  const float* h_b = (const float*)d_in[7];
  const float* out_w = (const float*)d_in[8];
  const float* out_b = (const float*)d_in[9];
  float* out = (float*)d_out;

  const size_t MB = 1ull << 20;
  char* base = (char*)d_ws;
  // [0,16M): contentT (dead after f-conv) then midT
  f16* contentT = (f16*)base;
  f16* midT     = (f16*)base;
  // [16M,48M): styrF f32 (dead after tcvt) -> hC bf16 [16,32M), fT [32,34M), gT [34,36M)
  float* styrF = (float*)(base + 16 * MB);
  unsigned short* hC = (unsigned short*)(base + 16 * MB);
  f16* fT = (f16*)(base + 32 * MB);
  f16* gT = (f16*)(base + 34 * MB);
  // [48M,64M): styrT
  f16* styrT = (f16*)(base + 48 * MB);
  // [64M,66M): f16 weights
  f16* fw16 = (f16*)(base + 64 * MB);
  f16* gw16 = fw16 + ND * NC;
  f16* hw16 = gw16 + ND * NC;
  f16* ow16 = hw16 + NC * NC;

  // 1. weights -> f16
  cvt_kernel<<<dim3((ND * NC + 255) / 256), 256, 0, stream>>>(f_w, fw16, ND * NC);
  cvt_kernel<<<dim3((ND * NC + 255) / 256), 256, 0, stream>>>(g_w, gw16, ND * NC);
  cvt_kernel<<<dim3((NC * NC + 255) / 256), 256, 0, stream>>>(h_w, hw16, NC * NC);
  cvt_kernel<<<dim3((NC * NC + 255) / 256), 256, 0, stream>>>(out_w, ow16, NC * NC);
  // 2. content -> contentT (pos-major f16)
  tcvt_kernel<<<dim3(HW / 64, NC / 64, NB), 256, 0, stream>>>(content, contentT);
  // 3. resize style (f32 ch-major)
  resize_kernel<<<dim3((NB * NC * HW + 255) / 256), 256, 0, stream>>>(style, styrF);
  // 4. styrF -> styrT (pos-major f16)
  tcvt_kernel<<<dim3(HW / 64, NC / 64, NB), 256, 0, stream>>>(styrF, styrT);
  // 5. f = f_w@content (pos-major out)
  convpm_kernel<<<dim3(HW / 256, 1, NB), 256, 0, stream>>>(contentT, fw16, f_b, fT);
  // 6. g = g_w@styr (pos-major out)
  convpm_kernel<<<dim3(HW / 256, 1, NB), 256, 0, stream>>>(styrT, gw16, g_b, gT);
  // 7. h = h_w@styr (ch-major bf16 out)
  convcm_kernel<unsigned short><<<dim3(NC / 64, HW / 256, NB), 256, 0, stream>>>(styrT, hw16, h_b, hC, NC);
  // 8. attention -> midT (pos-major f16)
  attn_kernel<<<dim3(NB * 64), 256, 0, stream>>>(fT, gT, hC, midT);
  // 9. out = out_w@mid (ch-major f32 out)
  convcm_kernel<float><<<dim3(NC / 64, HW / 256, NB), 256, 0, stream>>>(midT, ow16, out_b, out, NC);
}

// Round 3
// 318.141 us; speedup vs baseline: 7.1229x; 1.3605x over previous
//
#include <hip/hip_runtime.h>

#define NB 4
#define NC 512
#define ND 64
#define HW 4096
#define SPIN 6400

typedef _Float16 f16;
typedef _Float16 f16x8 __attribute__((ext_vector_type(8)));
typedef short s16x8 __attribute__((ext_vector_type(8)));
typedef float f32x4 __attribute__((ext_vector_type(4)));

__device__ __forceinline__ unsigned short f32_to_bf16(float x) {
  union { float f; unsigned u; } v; v.f = x;
  unsigned r = v.u + 0x7FFFu + ((v.u >> 16) & 1u);
  return (unsigned short)(r >> 16);
}

__device__ __forceinline__ void stv(float* p, float v) { *p = v; }
__device__ __forceinline__ void stv(f16* p, float v) { *p = (f16)v; }
__device__ __forceinline__ void stv(unsigned short* p, float v) { *p = f32_to_bf16(v); }

// ---------------- weight convert f32 -> f16 ----------------
__global__ __launch_bounds__(256) void cvt_kernel(const float* __restrict__ in,
                                                  f16* __restrict__ out, int n) {
  int i = blockIdx.x * 256 + threadIdx.x;
  if (i < n) out[i] = (f16)in[i];
}

// ---------------- transpose+cvt: f32 [b][512][4096] -> f16 [b][4096][512] ----------------
__global__ __launch_bounds__(256) void tcvt_kernel(const float* __restrict__ in,
                                                   f16* __restrict__ out) {
  __shared__ float Xs[64][65];
  int p0 = blockIdx.x * 64, c0 = blockIdx.y * 64, b = blockIdx.z;
  int t = threadIdx.x;
  const float* ib = in + ((size_t)b * NC + c0) * HW + p0;
  int pl = t & 63, cg = t >> 6;
#pragma unroll
  for (int k = 0; k < 16; ++k) {
    int c = cg * 16 + k;
    Xs[c][pl] = ib[(size_t)c * HW + pl];
  }
  __syncthreads();
  int p = t >> 2, cb = (t & 3) * 16;
  union { f16 h[16]; float4 q[2]; } u;
#pragma unroll
  for (int j = 0; j < 16; ++j) u.h[j] = (f16)Xs[cb + j][p];
  f16* ob = out + ((size_t)b * HW + p0 + p) * NC + c0 + cb;
  *(float4*)(ob) = u.q[0];
  *(float4*)(ob + 8) = u.q[1];
}

// ---------------- fused bilinear-resize(80->64) + transpose + cvt for style ----------------
// in: f32 [b][512][80][80] ; out: f16 [b][4096][512] pos-major
// block = (oy, 64-ch group, batch); computes out row-block [oy*64 .. +64)[c0..c0+64)
__global__ __launch_bounds__(256) void rstcvt_kernel(const float* __restrict__ X,
                                                     f16* __restrict__ Y) {
  __shared__ float Xs[64 * 165];  // odd stride 165: kills cb-group bank aliasing
  int oy = blockIdx.x, c0 = blockIdx.y * 64, b = blockIdx.z;
  float syf = fmaxf((oy + 0.5f) * 1.25f - 0.5f, 0.f);
  int y0 = (int)syf; int y1 = min(y0 + 1, 79); float wy = syf - (float)y0;
  int t = threadIdx.x;
  const float* Xb = X + ((size_t)b * NC + c0) * SPIN;
#pragma unroll
  for (int k = 0; k < 10; ++k) {
    int idx = t + k * 256;       // 0..2559 : 64ch x 2rows x 20 float4
    int c = idx / 40;
    int rem = idx - c * 40;
    int yy = rem / 20;
    int x4 = rem - yy * 20;
    int ysrc = yy ? y1 : y0;
    float4 v = *(const float4*)(Xb + (size_t)c * SPIN + ysrc * 80 + x4 * 4);
    float* d = Xs + c * 165 + yy * 82 + x4 * 4;
    d[0] = v.x; d[1] = v.y; d[2] = v.z; d[3] = v.w;
  }
  __syncthreads();
  int ox = t >> 2, cb = (t & 3) * 16;
  float sxf = fmaxf((ox + 0.5f) * 1.25f - 0.5f, 0.f);
  int x0 = (int)sxf; int x1 = min(x0 + 1, 79); float wx = sxf - (float)x0;
  union { f16 h[16]; float4 q[2]; } u;
#pragma unroll
  for (int j = 0; j < 16; ++j) {
    const float* base = Xs + (cb + j) * 165;
    float a0 = base[x0], a1 = base[x1];
    float b0 = base[82 + x0], b1 = base[82 + x1];
    float r0 = a0 + (a1 - a0) * wx;
    float r1 = b0 + (b1 - b0) * wx;
    u.h[j] = (f16)(r0 + (r1 - r0) * wy);
  }
  f16* ob = Y + ((size_t)b * HW + oy * 64 + ox) * NC + c0 + cb;
  *(float4*)(ob) = u.q[0];
  *(float4*)(ob + 8) = u.q[1];
}

// ---------------- conv1x1, position-major out (O=64): Y[b][p][o] ----------------
__global__ __launch_bounds__(256) void convpm_kernel(const f16* __restrict__ X,
                                                     const f16* __restrict__ W,
                                                     const float* __restrict__ bias,
                                                     f16* __restrict__ Y) {
  int b = blockIdx.z;
  int t = threadIdx.x, l = t & 63, w = t >> 6;
  int pw = blockIdx.x * 256 + w * 64;
  int l4 = l & 15, g = l >> 4;
  f32x4 acc[4][4] = {};
  const f16* Xb = X + ((size_t)b * HW + pw) * NC;
  for (int kk = 0; kk < 16; ++kk) {
    int co = kk * 32 + g * 8;
    f16x8 a[4], bb[4];
#pragma unroll
    for (int ms = 0; ms < 4; ++ms) a[ms] = *(const f16x8*)(Xb + (size_t)(ms * 16 + l4) * NC + co);
#pragma unroll
    for (int ct = 0; ct < 4; ++ct) bb[ct] = *(const f16x8*)(W + (size_t)(ct * 16 + l4) * NC + co);
#pragma unroll
    for (int ms = 0; ms < 4; ++ms)
#pragma unroll
      for (int ct = 0; ct < 4; ++ct)
        acc[ms][ct] = __builtin_amdgcn_mfma_f32_16x16x32_f16(a[ms], bb[ct], acc[ms][ct], 0, 0, 0);
  }
  float bv[4];
#pragma unroll
  for (int ct = 0; ct < 4; ++ct) bv[ct] = bias[ct * 16 + l4];
  f16* Yb = Y + ((size_t)b * HW + pw) * ND;
#pragma unroll
  for (int ms = 0; ms < 4; ++ms)
#pragma unroll
    for (int ct = 0; ct < 4; ++ct)
#pragma unroll
      for (int r = 0; r < 4; ++r)
        Yb[(size_t)(ms * 16 + g * 4 + r) * ND + ct * 16 + l4] = (f16)(acc[ms][ct][r] + bv[ct]);
}

// ---------------- conv1x1, channel-major out ----------------
template <typename OUT_T>
__global__ __launch_bounds__(256) void convcm_kernel(const f16* __restrict__ X,
                                                     const f16* __restrict__ W,
                                                     const float* __restrict__ bias,
                                                     OUT_T* __restrict__ Y, int O) {
  int b = blockIdx.z;
  int o0 = blockIdx.x * 64;
  int t = threadIdx.x, l = t & 63, w = t >> 6;
  int pw = blockIdx.y * 256 + w * 64;
  int l4 = l & 15, g = l >> 4;
  f32x4 acc[4][4] = {};
  const f16* Xb = X + ((size_t)b * HW + pw) * NC;
  const f16* Wb = W + (size_t)o0 * NC;
  for (int kk = 0; kk < 16; ++kk) {
    int co = kk * 32 + g * 8;
    f16x8 a[4], bb[4];
#pragma unroll
    for (int ms = 0; ms < 4; ++ms) a[ms] = *(const f16x8*)(Wb + (size_t)(ms * 16 + l4) * NC + co);
#pragma unroll
    for (int ct = 0; ct < 4; ++ct) bb[ct] = *(const f16x8*)(Xb + (size_t)(ct * 16 + l4) * NC + co);
#pragma unroll
    for (int ms = 0; ms < 4; ++ms)
#pragma unroll
      for (int ct = 0; ct < 4; ++ct)
        acc[ms][ct] = __builtin_amdgcn_mfma_f32_16x16x32_f16(a[ms], bb[ct], acc[ms][ct], 0, 0, 0);
  }
  float bv[4][4];
#pragma unroll
  for (int ms = 0; ms < 4; ++ms)
#pragma unroll
    for (int r = 0; r < 4; ++r) bv[ms][r] = bias[o0 + ms * 16 + g * 4 + r];
#pragma unroll
  for (int ms = 0; ms < 4; ++ms)
#pragma unroll
    for (int ct = 0; ct < 4; ++ct)
#pragma unroll
      for (int r = 0; r < 4; ++r) {
        float val = acc[ms][ct][r] + bv[ms][r];
        stv(&Y[((size_t)b * O + o0 + ms * 16 + g * 4 + r) * HW + pw + ct * 16 + l4], val);
      }
}

// ---------------- flash attention (MFMA, no max-tracking), 8 waves, csplit x2 ----------------
// FT,GT: f16 [b][4096][64]; HC: bf16 [b][512][4096]; MIDT: f16 [b][4096][512]
// grid 512: bid -> b=(bid&7)>>1 (XCD pinning), cs=bid&1, m-tile=bid>>3
__global__ __launch_bounds__(512, 4) void attn_kernel(const f16* __restrict__ FT,
                                                      const f16* __restrict__ GT,
                                                      const unsigned short* __restrict__ HC,
                                                      f16* __restrict__ MIDT) {
  __shared__ __align__(16) char KsB[128 * 128];  // 128 n-rows x 128B (64 f16), swizzled
  __shared__ __align__(16) char PsB[64 * 256];   // 64 m-rows x 256B (128 bf16), swizzled
  __shared__ float denP[8][16];
  int bid = blockIdx.x;
  int b = (bid & 7) >> 1;
  int cs = bid & 1;
  int m0 = (bid >> 3) * 64;
  int t = threadIdx.x, l = t & 63, w = t >> 6;
  int l4 = l & 15, g = l >> 4;
  int msq = w >> 1;        // QK: wave's m-fragment
  int nsq = (w & 1) * 4;   // QK: wave's 4 n-fragments base

  const f16* Fb = FT + ((size_t)b * HW + m0 + msq * 16 + l4) * ND + g * 8;
  f16x8 qa0 = *(const f16x8*)(Fb);
  f16x8 qa1 = *(const f16x8*)(Fb + 32);

  f32x4 acc[4][2] = {};
  float den_acc[4] = {0.f, 0.f, 0.f, 0.f};

  const f16* Gb = GT + (size_t)b * HW * ND;
  const unsigned short* Hb = HC + ((size_t)b * NC + cs * 256 + w * 32) * HW;

  for (int n0 = 0; n0 < HW; n0 += 128) {
    __syncthreads();  // prev-iter Ks/Ps fully consumed
#pragma unroll
    for (int i = 0; i < 2; ++i) {
      int idx = t + i * 512;
      int nl = idx >> 3, cc = idx & 7;
      f16x8 kv = *(const f16x8*)(Gb + (size_t)(n0 + nl) * ND + cc * 8);
      *(f16x8*)(KsB + ((nl * 128 + cc * 16) ^ ((nl & 7) << 4))) = kv;
    }
    __syncthreads();
    // S = Q K^T, P = exp(S) -> LDS (bf16), den partial in regs
    float dp[4] = {0.f, 0.f, 0.f, 0.f};
#pragma unroll
    for (int f = 0; f < 4; ++f) {
      int n = (nsq + f) * 16 + l4;
      int sw = (n & 7) << 4;
      f16x8 kb0 = *(const f16x8*)(KsB + ((n * 128 + g * 16) ^ sw));
      f16x8 kb1 = *(const f16x8*)(KsB + ((n * 128 + 64 + g * 16) ^ sw));
      f32x4 s = {};
      s = __builtin_amdgcn_mfma_f32_16x16x32_f16(qa0, kb0, s, 0, 0, 0);
      s = __builtin_amdgcn_mfma_f32_16x16x32_f16(qa1, kb1, s, 0, 0, 0);
#pragma unroll
      for (int r = 0; r < 4; ++r) {
        float p = __expf(s[r]);
        dp[r] += p;
        int row = msq * 16 + g * 4 + r;
        *(unsigned short*)(PsB + ((row * 256 + n * 2) ^ ((row & 7) << 4))) = f32_to_bf16(p);
      }
    }
#pragma unroll
    for (int r = 0; r < 4; ++r) {
      float v = dp[r];
      v += __shfl_xor(v, 1); v += __shfl_xor(v, 2);
      v += __shfl_xor(v, 4); v += __shfl_xor(v, 8);
      den_acc[r] += v;
    }
    __syncthreads();  // P visible
    // PV: wave owns 32 channels (cs*256 + w*32)
#pragma unroll
    for (int khh = 0; khh < 2; ++khh) {
      s16x8 pa[4][2];
#pragma unroll
      for (int ms = 0; ms < 4; ++ms) {
        int row = ms * 16 + l4;
        int sw = (row & 7) << 4;
        pa[ms][0] = *(const s16x8*)(PsB + ((row * 256 + khh * 128 + g * 16) ^ sw));
        pa[ms][1] = *(const s16x8*)(PsB + ((row * 256 + khh * 128 + 64 + g * 16) ^ sw));
      }
#pragma unroll
      for (int ct = 0; ct < 2; ++ct) {
        const unsigned short* hp = Hb + (size_t)(ct * 16 + l4) * HW + n0 + khh * 64 + g * 8;
        s16x8 vb0 = *(const s16x8*)(hp);
        s16x8 vb1 = *(const s16x8*)(hp + 32);
#pragma unroll
        for (int ms = 0; ms < 4; ++ms) {
          acc[ms][ct] = __builtin_amdgcn_mfma_f32_16x16x32_bf16(pa[ms][0], vb0, acc[ms][ct], 0, 0, 0);
          acc[ms][ct] = __builtin_amdgcn_mfma_f32_16x16x32_bf16(pa[ms][1], vb1, acc[ms][ct], 0, 0, 0);
        }
      }
    }
  }
  if (l4 == 0) {
#pragma unroll
    for (int r = 0; r < 4; ++r) denP[w][g * 4 + r] = den_acc[r];
  }
  __syncthreads();
  f16* Mb = MIDT + ((size_t)b * HW + m0) * NC + cs * 256 + w * 32;
#pragma unroll
  for (int ms = 0; ms < 4; ++ms)
#pragma unroll
    for (int r = 0; r < 4; ++r) {
      float rd = 1.f / (denP[2 * ms][g * 4 + r] + denP[2 * ms + 1][g * 4 + r]);
#pragma unroll
      for (int ct = 0; ct < 2; ++ct)
        Mb[(size_t)(ms * 16 + g * 4 + r) * NC + ct * 16 + l4] = (f16)(acc[ms][ct][r] * rd);
    }
}

extern "C" void kernel_launch(void* const* d_in, const int* in_sizes, int n_in,
                              void* d_out, int out_size, void* d_ws, size_t ws_size,
                              hipStream_t stream) {
  const float* content = (const float*)d_in[0];
  const float* style   = (const float*)d_in[1];
  const float* f_w = (const float*)d_in[2];
  const float* f_b = (const float*)d_in[3];
  const float* g_w = (const float*)d_in[4];
  const float* g_b = (const float*)d_in[5];
  const float* h_w = (const float*)d_in[6];
  const float* h_b = (const float*)d_in[7];
  const float* out_w = (const float*)d_in[8];
  const float* out_b = (const float*)d_in[9];
  float* out = (float*)d_out;

  const size_t MB = 1ull << 20;
  char* base = (char*)d_ws;
  f16* contentT = (f16*)base;            // [0,16M) dead after f-conv
  f16* midT     = (f16*)base;            // reuse
  unsigned short* hC = (unsigned short*)(base + 16 * MB);  // [16,32M)
  f16* fT = (f16*)(base + 32 * MB);
  f16* gT = (f16*)(base + 34 * MB);
  f16* styrT = (f16*)(base + 48 * MB);   // [48,64M)
  f16* fw16 = (f16*)(base + 64 * MB);
  f16* gw16 = fw16 + ND * NC;
  f16* hw16 = gw16 + ND * NC;
  f16* ow16 = hw16 + NC * NC;

  cvt_kernel<<<dim3((ND * NC + 255) / 256), 256, 0, stream>>>(f_w, fw16, ND * NC);
  cvt_kernel<<<dim3((ND * NC + 255) / 256), 256, 0, stream>>>(g_w, gw16, ND * NC);
  cvt_kernel<<<dim3((NC * NC + 255) / 256), 256, 0, stream>>>(h_w, hw16, NC * NC);
  cvt_kernel<<<dim3((NC * NC + 255) / 256), 256, 0, stream>>>(out_w, ow16, NC * NC);
  tcvt_kernel<<<dim3(HW / 64, NC / 64, NB), 256, 0, stream>>>(content, contentT);
  rstcvt_kernel<<<dim3(64, NC / 64, NB), 256, 0, stream>>>(style, styrT);
  convpm_kernel<<<dim3(HW / 256, 1, NB), 256, 0, stream>>>(contentT, fw16, f_b, fT);
  convpm_kernel<<<dim3(HW / 256, 1, NB), 256, 0, stream>>>(styrT, gw16, g_b, gT);
  convcm_kernel<unsigned short><<<dim3(NC / 64, HW / 256, NB), 256, 0, stream>>>(styrT, hw16, h_b, hC, NC);
  attn_kernel<<<dim3(512), 512, 0, stream>>>(fT, gT, hC, midT);
  convcm_kernel<float><<<dim3(NC / 64, HW / 256, NB), 256, 0, stream>>>(midT, ow16, out_b, out, NC);
}

// Round 4
// 291.695 us; speedup vs baseline: 7.7687x; 1.0907x over previous
//
#include <hip/hip_runtime.h>

#define NB 4
#define NC 512
#define ND 64
#define HW 4096
#define SPIN 6400

typedef _Float16 f16;
typedef _Float16 f16x8 __attribute__((ext_vector_type(8)));
typedef short s16x8 __attribute__((ext_vector_type(8)));
typedef float f32x4 __attribute__((ext_vector_type(4)));

__device__ __forceinline__ unsigned short f32_to_bf16(float x) {
  union { float f; unsigned u; } v; v.f = x;
  unsigned r = v.u + 0x7FFFu + ((v.u >> 16) & 1u);
  return (unsigned short)(r >> 16);
}

__device__ __forceinline__ void stv(float* p, float v) { *p = v; }
__device__ __forceinline__ void stv(f16* p, float v) { *p = (f16)v; }
__device__ __forceinline__ void stv(unsigned short* p, float v) { *p = f32_to_bf16(v); }

// ---------------- all weights f32 -> f16, one launch ----------------
// dst layout: f[0,32768) g[32768,65536) h[65536,327680) o[327680,589824)
__global__ __launch_bounds__(256) void cvtw_kernel(const float* __restrict__ fw,
                                                   const float* __restrict__ gw,
                                                   const float* __restrict__ hw,
                                                   const float* __restrict__ ow,
                                                   f16* __restrict__ dst) {
  int i = blockIdx.x * 256 + threadIdx.x;
  const float* src; int off;
  if (i < 32768) { src = fw; off = 0; }
  else if (i < 65536) { src = gw; off = 32768; }
  else if (i < 327680) { src = hw; off = 65536; }
  else { src = ow; off = 327680; }
  dst[i] = (f16)src[i - off];
}

// ---------------- transpose+cvt: f32 [b][512][4096] -> f16 [b][4096][512] ----------------
__global__ __launch_bounds__(256) void tcvt_kernel(const float* __restrict__ in,
                                                   f16* __restrict__ out) {
  __shared__ float Xs[64][65];
  int p0 = blockIdx.x * 64, c0 = blockIdx.y * 64, b = blockIdx.z;
  int t = threadIdx.x;
  const float* ib = in + ((size_t)b * NC + c0) * HW + p0;
  int pl = t & 63, cg = t >> 6;
#pragma unroll
  for (int k = 0; k < 16; ++k) {
    int c = cg * 16 + k;
    Xs[c][pl] = ib[(size_t)c * HW + pl];
  }
  __syncthreads();
  int p = t >> 2, cb = (t & 3) * 16;
  union { f16 h[16]; float4 q[2]; } u;
#pragma unroll
  for (int j = 0; j < 16; ++j) u.h[j] = (f16)Xs[cb + j][p];
  f16* ob = out + ((size_t)b * HW + p0 + p) * NC + c0 + cb;
  *(float4*)(ob) = u.q[0];
  *(float4*)(ob + 8) = u.q[1];
}

// ---------------- fused bilinear-resize(80->64) + transpose + cvt for style ----------------
__global__ __launch_bounds__(256) void rstcvt_kernel(const float* __restrict__ X,
                                                     f16* __restrict__ Y) {
  __shared__ float Xs[64 * 165];
  int oy = blockIdx.x, c0 = blockIdx.y * 64, b = blockIdx.z;
  float syf = fmaxf((oy + 0.5f) * 1.25f - 0.5f, 0.f);
  int y0 = (int)syf; int y1 = min(y0 + 1, 79); float wy = syf - (float)y0;
  int t = threadIdx.x;
  const float* Xb = X + ((size_t)b * NC + c0) * SPIN;
#pragma unroll
  for (int k = 0; k < 10; ++k) {
    int idx = t + k * 256;
    int c = idx / 40;
    int rem = idx - c * 40;
    int yy = rem / 20;
    int x4 = rem - yy * 20;
    int ysrc = yy ? y1 : y0;
    float4 v = *(const float4*)(Xb + (size_t)c * SPIN + ysrc * 80 + x4 * 4);
    float* d = Xs + c * 165 + yy * 82 + x4 * 4;
    d[0] = v.x; d[1] = v.y; d[2] = v.z; d[3] = v.w;
  }
  __syncthreads();
  int ox = t >> 2, cb = (t & 3) * 16;
  float sxf = fmaxf((ox + 0.5f) * 1.25f - 0.5f, 0.f);
  int x0 = (int)sxf; int x1 = min(x0 + 1, 79); float wx = sxf - (float)x0;
  union { f16 h[16]; float4 q[2]; } u;
#pragma unroll
  for (int j = 0; j < 16; ++j) {
    const float* base = Xs + (cb + j) * 165;
    float a0 = base[x0], a1 = base[x1];
    float b0 = base[82 + x0], b1 = base[82 + x1];
    float r0 = a0 + (a1 - a0) * wx;
    float r1 = b0 + (b1 - b0) * wx;
    u.h[j] = (f16)(r0 + (r1 - r0) * wy);
  }
  f16* ob = Y + ((size_t)b * HW + oy * 64 + ox) * NC + c0 + cb;
  *(float4*)(ob) = u.q[0];
  *(float4*)(ob + 8) = u.q[1];
}

// ---------------- f & g conv1x1 fused, position-major out (O=64) ----------------
__global__ __launch_bounds__(256) void convpm2_kernel(const f16* __restrict__ X0,
                                                      const f16* __restrict__ X1,
                                                      const f16* __restrict__ W01,
                                                      const float* __restrict__ b0,
                                                      const float* __restrict__ b1,
                                                      f16* __restrict__ Y0,
                                                      f16* __restrict__ Y1) {
  int sel = blockIdx.z >> 2;
  int b = blockIdx.z & 3;
  const f16* X = sel ? X1 : X0;
  const f16* W = W01 + sel * (ND * NC);
  const float* bias = sel ? b1 : b0;
  f16* Y = sel ? Y1 : Y0;
  int t = threadIdx.x, l = t & 63, w = t >> 6;
  int pw = blockIdx.x * 256 + w * 64;
  int l4 = l & 15, g = l >> 4;
  f32x4 acc[4][4] = {};
  const f16* Xb = X + ((size_t)b * HW + pw) * NC;
  for (int kk = 0; kk < 16; ++kk) {
    int co = kk * 32 + g * 8;
    f16x8 a[4], bb[4];
#pragma unroll
    for (int ms = 0; ms < 4; ++ms) a[ms] = *(const f16x8*)(Xb + (size_t)(ms * 16 + l4) * NC + co);
#pragma unroll
    for (int ct = 0; ct < 4; ++ct) bb[ct] = *(const f16x8*)(W + (size_t)(ct * 16 + l4) * NC + co);
#pragma unroll
    for (int ms = 0; ms < 4; ++ms)
#pragma unroll
      for (int ct = 0; ct < 4; ++ct)
        acc[ms][ct] = __builtin_amdgcn_mfma_f32_16x16x32_f16(a[ms], bb[ct], acc[ms][ct], 0, 0, 0);
  }
  float bv[4];
#pragma unroll
  for (int ct = 0; ct < 4; ++ct) bv[ct] = bias[ct * 16 + l4];
  f16* Yb = Y + ((size_t)b * HW + pw) * ND;
#pragma unroll
  for (int ms = 0; ms < 4; ++ms)
#pragma unroll
    for (int ct = 0; ct < 4; ++ct)
#pragma unroll
      for (int r = 0; r < 4; ++r)
        Yb[(size_t)(ms * 16 + g * 4 + r) * ND + ct * 16 + l4] = (f16)(acc[ms][ct][r] + bv[ct]);
}

// ---------------- conv1x1, channel-major out ----------------
template <typename OUT_T>
__global__ __launch_bounds__(256) void convcm_kernel(const f16* __restrict__ X,
                                                     const f16* __restrict__ W,
                                                     const float* __restrict__ bias,
                                                     OUT_T* __restrict__ Y, int O) {
  int b = blockIdx.z;
  int o0 = blockIdx.x * 64;
  int t = threadIdx.x, l = t & 63, w = t >> 6;
  int pw = blockIdx.y * 256 + w * 64;
  int l4 = l & 15, g = l >> 4;
  f32x4 acc[4][4] = {};
  const f16* Xb = X + ((size_t)b * HW + pw) * NC;
  const f16* Wb = W + (size_t)o0 * NC;
  for (int kk = 0; kk < 16; ++kk) {
    int co = kk * 32 + g * 8;
    f16x8 a[4], bb[4];
#pragma unroll
    for (int ms = 0; ms < 4; ++ms) a[ms] = *(const f16x8*)(Wb + (size_t)(ms * 16 + l4) * NC + co);
#pragma unroll
    for (int ct = 0; ct < 4; ++ct) bb[ct] = *(const f16x8*)(Xb + (size_t)(ct * 16 + l4) * NC + co);
#pragma unroll
    for (int ms = 0; ms < 4; ++ms)
#pragma unroll
      for (int ct = 0; ct < 4; ++ct)
        acc[ms][ct] = __builtin_amdgcn_mfma_f32_16x16x32_f16(a[ms], bb[ct], acc[ms][ct], 0, 0, 0);
  }
  float bv[4][4];
#pragma unroll
  for (int ms = 0; ms < 4; ++ms)
#pragma unroll
    for (int r = 0; r < 4; ++r) bv[ms][r] = bias[o0 + ms * 16 + g * 4 + r];
#pragma unroll
  for (int ms = 0; ms < 4; ++ms)
#pragma unroll
    for (int ct = 0; ct < 4; ++ct)
#pragma unroll
      for (int r = 0; r < 4; ++r) {
        float val = acc[ms][ct][r] + bv[ms][r];
        stv(&Y[((size_t)b * O + o0 + ms * 16 + g * 4 + r) * HW + pw + ct * 16 + l4], val);
      }
}

// ---------------- flash attention: K dbuf + async stage, 2 barriers/iter ----------------
// FT,GT: f16 [b][4096][64]; HC: bf16 [b][512][4096]; MIDT: f16 [b][4096][512]
__global__ __launch_bounds__(512, 4) void attn_kernel(const f16* __restrict__ FT,
                                                      const f16* __restrict__ GT,
                                                      const unsigned short* __restrict__ HC,
                                                      f16* __restrict__ MIDT) {
  __shared__ __align__(16) char KsB[2][128 * 128];
  __shared__ __align__(16) char PsB[64 * 256];
  __shared__ float denP[8][16];
  int bid = blockIdx.x;
  int b = (bid & 7) >> 1;   // XCD pinning: batch -> XCD pair
  int cs = bid & 1;
  int m0 = (bid >> 3) * 64;
  int t = threadIdx.x, l = t & 63, w = t >> 6;
  int l4 = l & 15, g = l >> 4;
  int msq = w >> 1;
  int nsq = (w & 1) * 4;

  const f16* Fb = FT + ((size_t)b * HW + m0 + msq * 16 + l4) * ND + g * 8;
  f16x8 qa0 = *(const f16x8*)(Fb);
  f16x8 qa1 = *(const f16x8*)(Fb + 32);

  f32x4 acc[4][2] = {};
  float den_acc[4] = {0.f, 0.f, 0.f, 0.f};

  const f16* Gb = GT + (size_t)b * HW * ND;
  const unsigned short* Hb = HC + ((size_t)b * NC + cs * 256 + w * 32) * HW;

  // per-thread fixed staging coords: thread stages rows nl0 and nl0+64, col-chunk cc0
  int nl0 = t >> 3, cc0 = t & 7;
  int ka0 = (nl0 * 128 + cc0 * 16) ^ ((nl0 & 7) << 4);
  const f16* gsrc0 = Gb + (size_t)nl0 * ND + cc0 * 8;

  const unsigned short* hb0 = Hb + (size_t)l4 * HW + g * 8;         // ct=0
  const unsigned short* hb1 = Hb + (size_t)(16 + l4) * HW + g * 8;  // ct=1

  // prologue: stage K tile 0 into buf 0
  {
    f16x8 k0 = *(const f16x8*)(gsrc0);
    f16x8 k1 = *(const f16x8*)(gsrc0 + (size_t)64 * ND);
    *(f16x8*)(KsB[0] + ka0) = k0;
    *(f16x8*)(KsB[0] + ka0 + 8192) = k1;
  }
  __syncthreads();

  int cur = 0;
  for (int it = 0; it < 32; ++it) {
    int n0 = it * 128;
    bool pre = (it < 31);
    // issue next K tile loads (latency spans whole iteration)
    f16x8 k0, k1;
    if (pre) {
      const f16* gs = gsrc0 + (size_t)(n0 + 128) * ND;
      k0 = *(const f16x8*)(gs);
      k1 = *(const f16x8*)(gs + (size_t)64 * ND);
    }
    // issue V loads for khh0 (latency hides under QK)
    s16x8 vb00 = *(const s16x8*)(hb0 + n0);
    s16x8 vb01 = *(const s16x8*)(hb0 + n0 + 32);
    s16x8 vb10 = *(const s16x8*)(hb1 + n0);
    s16x8 vb11 = *(const s16x8*)(hb1 + n0 + 32);

    // ---- QK + exp + P-store ----
    const char* Kc = KsB[cur];
#pragma unroll
    for (int f = 0; f < 4; ++f) {
      int n = (nsq + f) * 16 + l4;
      int sw = (n & 7) << 4;
      f16x8 kb0 = *(const f16x8*)(Kc + ((n * 128 + g * 16) ^ sw));
      f16x8 kb1 = *(const f16x8*)(Kc + ((n * 128 + 64 + g * 16) ^ sw));
      f32x4 s = {};
      s = __builtin_amdgcn_mfma_f32_16x16x32_f16(qa0, kb0, s, 0, 0, 0);
      s = __builtin_amdgcn_mfma_f32_16x16x32_f16(qa1, kb1, s, 0, 0, 0);
#pragma unroll
      for (int r = 0; r < 4; ++r) {
        float p = __expf(s[r]);
        den_acc[r] += p;  // per-lane partial; cross-lane reduce deferred to epilogue
        int row = msq * 16 + g * 4 + r;
        *(unsigned short*)(PsB + ((row * 256 + n * 2) ^ ((row & 7) << 4))) = f32_to_bf16(p);
      }
    }
    __syncthreads();  // A: P visible; K[cur^1] free (consumed at it-1)
    if (pre) {
      *(f16x8*)(KsB[cur ^ 1] + ka0) = k0;
      *(f16x8*)(KsB[cur ^ 1] + ka0 + 8192) = k1;
    }
    // ---- PV ----
    // issue khh1 V loads now (hide under khh0 MFMA)
    s16x8 wb00 = *(const s16x8*)(hb0 + n0 + 64);
    s16x8 wb01 = *(const s16x8*)(hb0 + n0 + 96);
    s16x8 wb10 = *(const s16x8*)(hb1 + n0 + 64);
    s16x8 wb11 = *(const s16x8*)(hb1 + n0 + 96);
#pragma unroll
    for (int khh = 0; khh < 2; ++khh) {
      s16x8 v00 = khh ? wb00 : vb00, v01 = khh ? wb01 : vb01;
      s16x8 v10 = khh ? wb10 : vb10, v11 = khh ? wb11 : vb11;
#pragma unroll
      for (int mh = 0; mh < 2; ++mh) {  // 2 m-frags at a time (VGPR cap)
        s16x8 pa[2][2];
#pragma unroll
        for (int mi = 0; mi < 2; ++mi) {
          int row = (mh * 2 + mi) * 16 + l4;
          int sw = (row & 7) << 4;
          pa[mi][0] = *(const s16x8*)(PsB + ((row * 256 + khh * 128 + g * 16) ^ sw));
          pa[mi][1] = *(const s16x8*)(PsB + ((row * 256 + khh * 128 + 64 + g * 16) ^ sw));
        }
        __builtin_amdgcn_s_setprio(1);
#pragma unroll
        for (int mi = 0; mi < 2; ++mi) {
          int ms = mh * 2 + mi;
          acc[ms][0] = __builtin_amdgcn_mfma_f32_16x16x32_bf16(pa[mi][0], v00, acc[ms][0], 0, 0, 0);
          acc[ms][0] = __builtin_amdgcn_mfma_f32_16x16x32_bf16(pa[mi][1], v01, acc[ms][0], 0, 0, 0);
          acc[ms][1] = __builtin_amdgcn_mfma_f32_16x16x32_bf16(pa[mi][0], v10, acc[ms][1], 0, 0, 0);
          acc[ms][1] = __builtin_amdgcn_mfma_f32_16x16x32_bf16(pa[mi][1], v11, acc[ms][1], 0, 0, 0);
        }
        __builtin_amdgcn_s_setprio(0);
      }
    }
    __syncthreads();  // B: K[cur^1] staged; P consumed
    cur ^= 1;
  }

  // deferred den reduction (within 16-lane l4 groups; g-groups are distinct rows)
#pragma unroll
  for (int r = 0; r < 4; ++r) {
    float v = den_acc[r];
    v += __shfl_xor(v, 1); v += __shfl_xor(v, 2);
    v += __shfl_xor(v, 4); v += __shfl_xor(v, 8);
    den_acc[r] = v;
  }
  if (l4 == 0) {
#pragma unroll
    for (int r = 0; r < 4; ++r) denP[w][g * 4 + r] = den_acc[r];
  }
  __syncthreads();
  f16* Mb = MIDT + ((size_t)b * HW + m0) * NC + cs * 256 + w * 32;
#pragma unroll
  for (int ms = 0; ms < 4; ++ms)
#pragma unroll
    for (int r = 0; r < 4; ++r) {
      float rd = 1.f / (denP[2 * ms][g * 4 + r] + denP[2 * ms + 1][g * 4 + r]);
#pragma unroll
      for (int ct = 0; ct < 2; ++ct)
        Mb[(size_t)(ms * 16 + g * 4 + r) * NC + ct * 16 + l4] = (f16)(acc[ms][ct][r] * rd);
    }
}

extern "C" void kernel_launch(void* const* d_in, const int* in_sizes, int n_in,
                              void* d_out, int out_size, void* d_ws, size_t ws_size,
                              hipStream_t stream) {
  const float* content = (const float*)d_in[0];
  const float* style   = (const float*)d_in[1];
  const float* f_w = (const float*)d_in[2];
  const float* f_b = (const float*)d_in[3];
  const float* g_w = (const float*)d_in[4];
  const float* g_b = (const float*)d_in[5];
  const float* h_w = (const float*)d_in[6];
  const float* h_b = (const float*)d_in[7];
  const float* out_w = (const float*)d_in[8];
  const float* out_b = (const float*)d_in[9];
  float* out = (float*)d_out;

  const size_t MB = 1ull << 20;
  char* base = (char*)d_ws;
  f16* contentT = (f16*)base;            // [0,16M) dead after f-conv
  f16* midT     = (f16*)base;            // reuse
  unsigned short* hC = (unsigned short*)(base + 16 * MB);  // [16,32M)
  f16* fT = (f16*)(base + 32 * MB);
  f16* gT = (f16*)(base + 34 * MB);
  f16* styrT = (f16*)(base + 48 * MB);   // [48,64M)
  f16* w16 = (f16*)(base + 64 * MB);     // contiguous: f,g,h,out
  f16* fw16 = w16;
  f16* gw16 = w16 + 32768;
  f16* hw16 = w16 + 65536;
  f16* ow16 = w16 + 327680;

  cvtw_kernel<<<dim3(589824 / 256), 256, 0, stream>>>(f_w, g_w, h_w, out_w, w16);
  tcvt_kernel<<<dim3(HW / 64, NC / 64, NB), 256, 0, stream>>>(content, contentT);
  rstcvt_kernel<<<dim3(64, NC / 64, NB), 256, 0, stream>>>(style, styrT);
  convpm2_kernel<<<dim3(HW / 256, 1, 2 * NB), 256, 0, stream>>>(contentT, styrT, fw16, f_b, g_b, fT, gT);
  convcm_kernel<unsigned short><<<dim3(NC / 64, HW / 256, NB), 256, 0, stream>>>(styrT, hw16, h_b, hC, NC);
  attn_kernel<<<dim3(512), 512, 0, stream>>>(fT, gT, hC, midT);
  convcm_kernel<float><<<dim3(NC / 64, HW / 256, NB), 256, 0, stream>>>(midT, ow16, out_b, out, NC);
}